// Round 1
// baseline (333.634 us; speedup 1.0000x reference)
//
#include <hip/hip_runtime.h>
#include <math.h>

// Problem dims (fixed)
#define B     4096
#define NIN   512
#define L     16
#define N     512
#define K     32
#define NOUT  256
#define TOTAL (NIN + L * N)   // 8704
#define BROWS 4               // batch rows per block (float4 lanes)
#define BLOCK 512             // one neuron per thread per layer

__device__ __forceinline__ float sigmoidf_fast(float z) {
    return 1.0f / (1.0f + __expf(-z));
}

// buf[c] holds column c of the activation buffer for the block's 4 batch rows:
// buf[c] = {row0, row1, row2, row3}. One ds_read_b128 serves 4 MACs.
__global__ __launch_bounds__(BLOCK, 1)
void ffnet_kernel(const float* __restrict__ x,
                  const float* __restrict__ W,
                  const float* __restrict__ b,
                  const float* __restrict__ W_out,
                  const float* __restrict__ b_out,
                  const int*   __restrict__ idx,
                  const int*   __restrict__ idx_out,
                  float* __restrict__ out)
{
    __shared__ float4 buf[TOTAL];   // 8704 * 16 B = 136 KB

    const int t  = threadIdx.x;
    const int r0 = blockIdx.x * BROWS;

    // ---- stage x into transposed LDS: thread t owns column c = t (NIN == BLOCK)
    {
        float4 v;
        v.x = x[(size_t)(r0 + 0) * NIN + t];
        v.y = x[(size_t)(r0 + 1) * NIN + t];
        v.z = x[(size_t)(r0 + 2) * NIN + t];
        v.w = x[(size_t)(r0 + 3) * NIN + t];
        buf[t] = v;
    }
    __syncthreads();

    // ---- 16 hidden layers; thread t computes neuron n = t for all 4 rows.
    // Reads come from columns < NIN + l*N, writes go to NIN + l*N + n:
    // disjoint, so only ONE barrier per layer (after the write).
    for (int l = 0; l < L; ++l) {
        const int4*   ip = (const int4*)  (idx + ((size_t)l * N + t) * K);
        const float4* wp = (const float4*)(W   + ((size_t)l * N + t) * K);

        float4 acc = make_float4(0.f, 0.f, 0.f, 0.f);
        #pragma unroll
        for (int kk = 0; kk < K / 4; ++kk) {
            const int4   i4 = ip[kk];
            const float4 w4 = wp[kk];
            float4 v;
            v = buf[i4.x];
            acc.x = fmaf(v.x, w4.x, acc.x); acc.y = fmaf(v.y, w4.x, acc.y);
            acc.z = fmaf(v.z, w4.x, acc.z); acc.w = fmaf(v.w, w4.x, acc.w);
            v = buf[i4.y];
            acc.x = fmaf(v.x, w4.y, acc.x); acc.y = fmaf(v.y, w4.y, acc.y);
            acc.z = fmaf(v.z, w4.y, acc.z); acc.w = fmaf(v.w, w4.y, acc.w);
            v = buf[i4.z];
            acc.x = fmaf(v.x, w4.z, acc.x); acc.y = fmaf(v.y, w4.z, acc.y);
            acc.z = fmaf(v.z, w4.z, acc.z); acc.w = fmaf(v.w, w4.z, acc.w);
            v = buf[i4.w];
            acc.x = fmaf(v.x, w4.w, acc.x); acc.y = fmaf(v.y, w4.w, acc.y);
            acc.z = fmaf(v.z, w4.w, acc.z); acc.w = fmaf(v.w, w4.w, acc.w);
        }

        const float bb = b[l * N + t];
        float4 o;
        o.x = sigmoidf_fast(acc.x + bb);
        o.y = sigmoidf_fast(acc.y + bb);
        o.z = sigmoidf_fast(acc.z + bb);
        o.w = sigmoidf_fast(acc.w + bb);
        buf[NIN + l * N + t] = o;
        __syncthreads();
    }

    // ---- output layer: threads 0..NOUT-1, neuron o = t
    if (t < NOUT) {
        const int4*   ip = (const int4*)  (idx_out + (size_t)t * K);
        const float4* wp = (const float4*)(W_out   + (size_t)t * K);

        float4 acc = make_float4(0.f, 0.f, 0.f, 0.f);
        #pragma unroll
        for (int kk = 0; kk < K / 4; ++kk) {
            const int4   i4 = ip[kk];
            const float4 w4 = wp[kk];
            float4 v;
            v = buf[i4.x];
            acc.x = fmaf(v.x, w4.x, acc.x); acc.y = fmaf(v.y, w4.x, acc.y);
            acc.z = fmaf(v.z, w4.x, acc.z); acc.w = fmaf(v.w, w4.x, acc.w);
            v = buf[i4.y];
            acc.x = fmaf(v.x, w4.y, acc.x); acc.y = fmaf(v.y, w4.y, acc.y);
            acc.z = fmaf(v.z, w4.y, acc.z); acc.w = fmaf(v.w, w4.y, acc.w);
            v = buf[i4.z];
            acc.x = fmaf(v.x, w4.z, acc.x); acc.y = fmaf(v.y, w4.z, acc.y);
            acc.z = fmaf(v.z, w4.z, acc.z); acc.w = fmaf(v.w, w4.z, acc.w);
            v = buf[i4.w];
            acc.x = fmaf(v.x, w4.w, acc.x); acc.y = fmaf(v.y, w4.w, acc.y);
            acc.z = fmaf(v.z, w4.w, acc.z); acc.w = fmaf(v.w, w4.w, acc.w);
        }

        const float bb = b_out[t];
        out[(size_t)(r0 + 0) * NOUT + t] = sigmoidf_fast(acc.x + bb);
        out[(size_t)(r0 + 1) * NOUT + t] = sigmoidf_fast(acc.y + bb);
        out[(size_t)(r0 + 2) * NOUT + t] = sigmoidf_fast(acc.z + bb);
        out[(size_t)(r0 + 3) * NOUT + t] = sigmoidf_fast(acc.w + bb);
    }
}

extern "C" void kernel_launch(void* const* d_in, const int* in_sizes, int n_in,
                              void* d_out, int out_size, void* d_ws, size_t ws_size,
                              hipStream_t stream) {
    const float* x     = (const float*)d_in[0];   // (B, NIN)
    const float* W     = (const float*)d_in[1];   // (L, N, K)
    const float* b     = (const float*)d_in[2];   // (L, N)
    const float* W_out = (const float*)d_in[3];   // (NOUT, K)
    const float* b_out = (const float*)d_in[4];   // (NOUT,)
    const int*   idx   = (const int*)d_in[5];     // (L, N, K)
    const int*   idx_o = (const int*)d_in[6];     // (NOUT, K)
    float* out = (float*)d_out;                   // (B, NOUT)

    ffnet_kernel<<<dim3(B / BROWS), dim3(BLOCK), 0, stream>>>(
        x, W, b, W_out, b_out, idx, idx_o, out);
}

// Round 2
// 310.711 us; speedup vs baseline: 1.0738x; 1.0738x over previous
//
#include <hip/hip_runtime.h>
#include <hip/hip_fp16.h>
#include <math.h>

// Problem dims (fixed)
#define B     4096
#define NIN   512
#define L     16
#define N     512
#define K     32
#define NOUT  256
#define TOTAL (NIN + L * N)   // 8704
#define BROWS 4               // batch rows per block
#define BLOCK 512             // one neuron per thread per layer

// 4 fp16 values (8 B) — one ds_read_b64 fetches all 4 batch rows of a column.
typedef __attribute__((ext_vector_type(4))) _Float16 h4;

__device__ __forceinline__ float sigmoidf_fast(float z) {
    return 1.0f / (1.0f + __expf(-z));
}

// buf[c] = {row0, row1, row2, row3} in fp16. 8 B/column:
//   - LDS footprint 8704*8 = 68 KB -> 2 blocks/CU (16 waves, 2x latency hiding)
//   - bank group = c mod 16 -> 4-way conflicts instead of 8-way (fp32x4 was 16 B)
__global__ __launch_bounds__(BLOCK, 4)
void ffnet_kernel(const float* __restrict__ x,
                  const float* __restrict__ W,
                  const float* __restrict__ b,
                  const float* __restrict__ W_out,
                  const float* __restrict__ b_out,
                  const int*   __restrict__ idx,
                  const int*   __restrict__ idx_out,
                  float* __restrict__ out)
{
    __shared__ h4 buf[TOTAL];   // 68 KB

    const int t  = threadIdx.x;
    const int r0 = blockIdx.x * BROWS;

    // ---- stage x into transposed fp16 LDS: thread t owns column c = t (NIN == BLOCK)
    {
        h4 v;
        v.x = (_Float16)x[(size_t)(r0 + 0) * NIN + t];
        v.y = (_Float16)x[(size_t)(r0 + 1) * NIN + t];
        v.z = (_Float16)x[(size_t)(r0 + 2) * NIN + t];
        v.w = (_Float16)x[(size_t)(r0 + 3) * NIN + t];
        buf[t] = v;
    }
    __syncthreads();

    // ---- 16 hidden layers; thread t computes neuron n = t for all 4 rows.
    // Reads come from columns < NIN + l*N, writes go to NIN + l*N + n:
    // disjoint, so only ONE barrier per layer (after the write).
    for (int l = 0; l < L; ++l) {
        const int4*   ip = (const int4*)  (idx + ((size_t)l * N + t) * K);
        const float4* wp = (const float4*)(W   + ((size_t)l * N + t) * K);

        float4 acc = make_float4(0.f, 0.f, 0.f, 0.f);
        #pragma unroll
        for (int kk = 0; kk < K / 4; ++kk) {
            const int4   i4 = ip[kk];
            const float4 w4 = wp[kk];
            h4 v;
            v = buf[i4.x];
            acc.x = fmaf((float)v.x, w4.x, acc.x); acc.y = fmaf((float)v.y, w4.x, acc.y);
            acc.z = fmaf((float)v.z, w4.x, acc.z); acc.w = fmaf((float)v.w, w4.x, acc.w);
            v = buf[i4.y];
            acc.x = fmaf((float)v.x, w4.y, acc.x); acc.y = fmaf((float)v.y, w4.y, acc.y);
            acc.z = fmaf((float)v.z, w4.y, acc.z); acc.w = fmaf((float)v.w, w4.y, acc.w);
            v = buf[i4.z];
            acc.x = fmaf((float)v.x, w4.z, acc.x); acc.y = fmaf((float)v.y, w4.z, acc.y);
            acc.z = fmaf((float)v.z, w4.z, acc.z); acc.w = fmaf((float)v.w, w4.z, acc.w);
            v = buf[i4.w];
            acc.x = fmaf((float)v.x, w4.w, acc.x); acc.y = fmaf((float)v.y, w4.w, acc.y);
            acc.z = fmaf((float)v.z, w4.w, acc.z); acc.w = fmaf((float)v.w, w4.w, acc.w);
        }

        const float bb = b[l * N + t];
        h4 o;
        o.x = (_Float16)sigmoidf_fast(acc.x + bb);
        o.y = (_Float16)sigmoidf_fast(acc.y + bb);
        o.z = (_Float16)sigmoidf_fast(acc.z + bb);
        o.w = (_Float16)sigmoidf_fast(acc.w + bb);
        buf[NIN + l * N + t] = o;
        __syncthreads();
    }

    // ---- output layer: threads 0..NOUT-1, neuron o = t. fp32 out.
    if (t < NOUT) {
        const int4*   ip = (const int4*)  (idx_out + (size_t)t * K);
        const float4* wp = (const float4*)(W_out   + (size_t)t * K);

        float4 acc = make_float4(0.f, 0.f, 0.f, 0.f);
        #pragma unroll
        for (int kk = 0; kk < K / 4; ++kk) {
            const int4   i4 = ip[kk];
            const float4 w4 = wp[kk];
            h4 v;
            v = buf[i4.x];
            acc.x = fmaf((float)v.x, w4.x, acc.x); acc.y = fmaf((float)v.y, w4.x, acc.y);
            acc.z = fmaf((float)v.z, w4.x, acc.z); acc.w = fmaf((float)v.w, w4.x, acc.w);
            v = buf[i4.y];
            acc.x = fmaf((float)v.x, w4.y, acc.x); acc.y = fmaf((float)v.y, w4.y, acc.y);
            acc.z = fmaf((float)v.z, w4.y, acc.z); acc.w = fmaf((float)v.w, w4.y, acc.w);
            v = buf[i4.z];
            acc.x = fmaf((float)v.x, w4.z, acc.x); acc.y = fmaf((float)v.y, w4.z, acc.y);
            acc.z = fmaf((float)v.z, w4.z, acc.z); acc.w = fmaf((float)v.w, w4.z, acc.w);
            v = buf[i4.w];
            acc.x = fmaf((float)v.x, w4.w, acc.x); acc.y = fmaf((float)v.y, w4.w, acc.y);
            acc.z = fmaf((float)v.z, w4.w, acc.z); acc.w = fmaf((float)v.w, w4.w, acc.w);
        }

        const float bb = b_out[t];
        out[(size_t)(r0 + 0) * NOUT + t] = sigmoidf_fast(acc.x + bb);
        out[(size_t)(r0 + 1) * NOUT + t] = sigmoidf_fast(acc.y + bb);
        out[(size_t)(r0 + 2) * NOUT + t] = sigmoidf_fast(acc.z + bb);
        out[(size_t)(r0 + 3) * NOUT + t] = sigmoidf_fast(acc.w + bb);
    }
}

extern "C" void kernel_launch(void* const* d_in, const int* in_sizes, int n_in,
                              void* d_out, int out_size, void* d_ws, size_t ws_size,
                              hipStream_t stream) {
    const float* x     = (const float*)d_in[0];   // (B, NIN)
    const float* W     = (const float*)d_in[1];   // (L, N, K)
    const float* b     = (const float*)d_in[2];   // (L, N)
    const float* W_out = (const float*)d_in[3];   // (NOUT, K)
    const float* b_out = (const float*)d_in[4];   // (NOUT,)
    const int*   idx   = (const int*)d_in[5];     // (L, N, K)
    const int*   idx_o = (const int*)d_in[6];     // (NOUT, K)
    float* out = (float*)d_out;                   // (B, NOUT)

    ffnet_kernel<<<dim3(B / BROWS), dim3(BLOCK), 0, stream>>>(
        x, W, b, W_out, b_out, idx, idx_o, out);
}

// Round 3
// 160.062 us; speedup vs baseline: 2.0844x; 1.9412x over previous
//
#include <hip/hip_runtime.h>
#include <hip/hip_fp16.h>
#include <math.h>

// Problem dims (fixed)
#define B     4096
#define NIN   512
#define L     16
#define N     512
#define K     32
#define NOUT  256
#define TOTAL (NIN + L * N)   // 8704
#define BROWS 4               // batch rows per block
#define BLOCK 512             // one neuron per thread per layer

typedef __attribute__((ext_vector_type(4))) _Float16 h4;        // 8 B: 4 batch rows of one column
typedef __attribute__((ext_vector_type(8))) _Float16 h8;        // 16 B: 8 packed fp16 weights
typedef __attribute__((ext_vector_type(8))) unsigned short u16x8; // 16 B: 8 packed int16 indices

__device__ __forceinline__ float sigmoidf_fast(float z) {
    return 1.0f / (1.0f + __expf(-z));
}

// ---- repack: idx int32 -> uint16, W fp32 -> fp16 (indices < 8704 fit u16;
// W ~ N(0,0.2), fp16 rel err 5e-4 — negligible vs 1.9e-2 threshold).
// Runs every call (ws is re-poisoned); ~3 MB of traffic, trivial cost.
__global__ void repack_kernel(const float* __restrict__ W,
                              const int*   __restrict__ idx,
                              const float* __restrict__ W_out,
                              const int*   __restrict__ idx_out,
                              _Float16* __restrict__ wh,
                              unsigned short* __restrict__ i16,
                              _Float16* __restrict__ who,
                              unsigned short* __restrict__ io16)
{
    int g = blockIdx.x * 256 + threadIdx.x;
    if (g < L * N * K) {
        wh[g]  = (_Float16)W[g];
        i16[g] = (unsigned short)idx[g];
    } else {
        int h = g - L * N * K;
        if (h < NOUT * K) {
            who[h]  = (_Float16)W_out[h];
            io16[h] = (unsigned short)idx_out[h];
        }
    }
}

// buf[c] = {row0..row3} fp16 (8 B). 68 KB -> 2 blocks/CU.
// Per layer per thread: 4x dwordx4 idx (prefetched one layer ahead) +
// 4x dwordx4 W (inline) + 32 ds_read_b64 gathers + 128 FMA.
__global__ __launch_bounds__(BLOCK, 4)
void ffnet_kernel(const float* __restrict__ x,
                  const float* __restrict__ b,
                  const float* __restrict__ b_out,
                  const _Float16*       __restrict__ wh,
                  const unsigned short* __restrict__ i16,
                  const _Float16*       __restrict__ who,
                  const unsigned short* __restrict__ io16,
                  float* __restrict__ out)
{
    __shared__ h4 buf[TOTAL];   // 68 KB

    const int t  = threadIdx.x;
    const int r0 = blockIdx.x * BROWS;

    // ---- stage x (transposed): thread t owns column t (NIN == BLOCK)
    {
        h4 v;
        v.x = (_Float16)x[(size_t)(r0 + 0) * NIN + t];
        v.y = (_Float16)x[(size_t)(r0 + 1) * NIN + t];
        v.z = (_Float16)x[(size_t)(r0 + 2) * NIN + t];
        v.w = (_Float16)x[(size_t)(r0 + 3) * NIN + t];
        buf[t] = v;
    }

    // ---- prefetch layer 0 indices (before the barrier: latency overlaps it)
    u16x8 ni[4];
    {
        const u16x8* ip = (const u16x8*)(i16 + (size_t)t * K);
        ni[0] = ip[0]; ni[1] = ip[1]; ni[2] = ip[2]; ni[3] = ip[3];
    }
    __syncthreads();

#define GATHER8(CI, W8)                                                        \
    {                                                                          \
        _Pragma("unroll")                                                      \
        for (int j = 0; j < 8; ++j) {                                          \
            const int   c = (int)(CI)[j];                                      \
            const float w = (float)(W8)[j];                                    \
            const h4    v = buf[c];                                            \
            acc.x = fmaf((float)v.x, w, acc.x);                                \
            acc.y = fmaf((float)v.y, w, acc.y);                                \
            acc.z = fmaf((float)v.z, w, acc.z);                                \
            acc.w = fmaf((float)v.w, w, acc.w);                                \
        }                                                                      \
    }

    // ---- 16 hidden layers; thread t = neuron t. Writes go past all reads:
    // one barrier per layer.
    for (int l = 0; l < L; ++l) {
        u16x8 ci[4];
        ci[0] = ni[0]; ci[1] = ni[1]; ci[2] = ni[2]; ci[3] = ni[3];

        const h8* wp = (const h8*)(wh + ((size_t)l * N + t) * K);
        const h8 w0 = wp[0], w1 = wp[1], w2 = wp[2], w3 = wp[3];

        // prefetch next layer's indices — lands during this layer's math
        if (l + 1 < L) {
            const u16x8* np = (const u16x8*)(i16 + ((size_t)(l + 1) * N + t) * K);
            ni[0] = np[0]; ni[1] = np[1]; ni[2] = np[2]; ni[3] = np[3];
        }

        float4 acc = make_float4(0.f, 0.f, 0.f, 0.f);
        GATHER8(ci[0], w0)
        GATHER8(ci[1], w1)
        GATHER8(ci[2], w2)
        GATHER8(ci[3], w3)

        const float bb = b[l * N + t];
        h4 o;
        o.x = (_Float16)sigmoidf_fast(acc.x + bb);
        o.y = (_Float16)sigmoidf_fast(acc.y + bb);
        o.z = (_Float16)sigmoidf_fast(acc.z + bb);
        o.w = (_Float16)sigmoidf_fast(acc.w + bb);
        buf[NIN + l * N + t] = o;
        __syncthreads();
    }

    // ---- output layer: threads 0..NOUT-1
    if (t < NOUT) {
        const u16x8* ip = (const u16x8*)(io16 + (size_t)t * K);
        const h8*    wp = (const h8*)   (who  + (size_t)t * K);
        const u16x8 i0 = ip[0], i1 = ip[1], i2 = ip[2], i3 = ip[3];
        const h8    w0 = wp[0], w1 = wp[1], w2 = wp[2], w3 = wp[3];

        float4 acc = make_float4(0.f, 0.f, 0.f, 0.f);
        GATHER8(i0, w0)
        GATHER8(i1, w1)
        GATHER8(i2, w2)
        GATHER8(i3, w3)

        const float bb = b_out[t];
        out[(size_t)(r0 + 0) * NOUT + t] = sigmoidf_fast(acc.x + bb);
        out[(size_t)(r0 + 1) * NOUT + t] = sigmoidf_fast(acc.y + bb);
        out[(size_t)(r0 + 2) * NOUT + t] = sigmoidf_fast(acc.z + bb);
        out[(size_t)(r0 + 3) * NOUT + t] = sigmoidf_fast(acc.w + bb);
    }
#undef GATHER8
}

extern "C" void kernel_launch(void* const* d_in, const int* in_sizes, int n_in,
                              void* d_out, int out_size, void* d_ws, size_t ws_size,
                              hipStream_t stream) {
    const float* x     = (const float*)d_in[0];   // (B, NIN)
    const float* W     = (const float*)d_in[1];   // (L, N, K)
    const float* b     = (const float*)d_in[2];   // (L, N)
    const float* W_out = (const float*)d_in[3];   // (NOUT, K)
    const float* b_out = (const float*)d_in[4];   // (NOUT,)
    const int*   idx   = (const int*)d_in[5];     // (L, N, K)
    const int*   idx_o = (const int*)d_in[6];     // (NOUT, K)
    float* out = (float*)d_out;                   // (B, NOUT)

    // workspace layout (1.03 MB total)
    char* ws = (char*)d_ws;
    _Float16*       wh   = (_Float16*)      (ws);                         // 512 KB
    unsigned short* i16  = (unsigned short*)(ws + 524288);                // 512 KB
    _Float16*       who  = (_Float16*)      (ws + 1048576);               // 16 KB
    unsigned short* io16 = (unsigned short*)(ws + 1048576 + 16384);       // 16 KB

    const int total_pack = L * N * K + NOUT * K;   // 270336
    repack_kernel<<<dim3((total_pack + 255) / 256), dim3(256), 0, stream>>>(
        W, idx, W_out, idx_o, wh, i16, who, io16);

    ffnet_kernel<<<dim3(B / BROWS), dim3(BLOCK), 0, stream>>>(
        x, b, b_out, wh, i16, who, io16, out);
}